// Round 5
// baseline (120.631 us; speedup 1.0000x reference)
//
#include <hip/hip_runtime.h>
#include <stdint.h>

#define TT 64
#define BB 128
#define VV 4880
#define NF4 (VV / 4)          // 1220 float4 per row
#define NROWS (TT * BB)       // 8192
#define LOG_EPS_F 1e-8f
#define NBUCKET 64
#define NQ 9
#define THR0 0.992f           // expect ~39 candidate lanes/row (band 20..64)
#define SLOTS 64

// Pack (value, row-local idx) so that u64 max-compare == (value desc, idx asc).
// y_hat > 0 so float bits are monotonic in value. idx < 4880 fits in 13 bits.
__device__ __forceinline__ uint64_t mkkey(float v, int idx) {
  return ((uint64_t)__float_as_uint(v) << 13) | (uint64_t)(8191 - idx);
}

__device__ __forceinline__ int lane_prefix(unsigned long long m) {
  return __builtin_amdgcn_mbcnt_hi((unsigned)(m >> 32),
         __builtin_amdgcn_mbcnt_lo((unsigned)m, 0));
}

__global__ __launch_bounds__(256) void pass_kernel(
    const float* __restrict__ yhat, const float* __restrict__ yy,
    const float* __restrict__ length, float* __restrict__ bucket) {
  __shared__ int fbuf_all[4][SLOTS];   // per-wave candidate f-index list (1 KB)

  const int wid  = threadIdx.x >> 6;    // wave 0..3
  const int lane = threadIdx.x & 63;
  const int row  = blockIdx.x * 4 + wid;   // row = t*B + b
  const int b    = row & (BB - 1);
  const float4* h4 = (const float4*)(yhat + (size_t)row * VV);
  const float4* y4 = (const float4*)(yy   + (size_t)row * VV);
  int* fbuf = fbuf_all[wid];

  float logsum = 0.0f;   // sum of log(selected); ce = -logsum
  float nposf  = 0.0f;
  float thr    = THR0;
  int   cnt    = 0;      // wave-uniform count of taken lane-slots

  // per-chunk lane-max filter: 1 cmp + 1 ballot per float4, store f only
  auto filt = [&](float4 h, int f) {
    float hm = fmaxf(fmaxf(h.x, h.y), fmaxf(h.z, h.w));
    bool take = hm > thr;
    unsigned long long m = __ballot(take);
    if (m) {
      if (take) {
        int s = cnt + lane_prefix(m);
        if (s < SLOTS) fbuf[s] = f;
      }
      cnt += __popcll(m);
    }
  };
  auto bce = [&](float4 h, float4 v) {
    float a0 = ((v.x != 0.0f) ? h.x : (1.0f - h.x)) + LOG_EPS_F;
    float a1 = ((v.y != 0.0f) ? h.y : (1.0f - h.y)) + LOG_EPS_F;
    float a2 = ((v.z != 0.0f) ? h.z : (1.0f - h.z)) + LOG_EPS_F;
    float a3 = ((v.w != 0.0f) ? h.w : (1.0f - h.w)) + LOG_EPS_F;
    logsum += __logf((a0 * a1) * (a2 * a3));   // product >= 1e-16, no underflow
    nposf  += (v.x + v.y) + (v.z + v.w);       // y is exactly 0.0/1.0
  };

  // ---- main scan: 4-chunk batches (8 loads in flight), low VALU ----
  #pragma unroll 1
  for (int i = 0; i < 16; i += 4) {
    const int f = lane + 64 * i;
    float4 h0 = h4[f], h1 = h4[f + 64], h2 = h4[f + 128], h3 = h4[f + 192];
    float4 v0 = y4[f], v1 = y4[f + 64], v2 = y4[f + 128], v3 = y4[f + 192];
    bce(h0, v0); filt(h0, f);
    bce(h1, v1); filt(h1, f + 64);
    bce(h2, v2); filt(h2, f + 128);
    bce(h3, v3); filt(h3, f + 192);
  }
  #pragma unroll
  for (int i = 16; i < 19; ++i) {
    const int f = lane + 64 * i;
    float4 h0 = h4[f], v0 = y4[f];
    bce(h0, v0); filt(h0, f);
  }
  {
    // chunk 19: only lanes 0-3 in range; others fed neutral values
    const bool act = (lane < 4);
    const int f_ = act ? (1216 + lane) : 1216;
    float4 h0 = h4[f_], v0 = y4[f_];
    if (!act) { h0 = make_float4(0, 0, 0, 0); v0 = make_float4(0, 0, 0, 0); }
    bce(h0, v0);                    // inactive: a=1.0 exactly -> log 0
    filt(h0, 1216 + lane);          // inactive: hm=0 -> no take
  }

  // ---- per-wave retry (wave-uniform; rare) ----
  // Valid when 20 <= cnt <= SLOTS: >=20 lanes each holding >=1 elem > thr
  // guarantees the top-20 elements are all > thr and fully captured.
  int attempt = 0;
  while ((cnt < 20 || cnt > SLOTS) && attempt < 8) {
    thr = (cnt < 20) ? 1.0f - (1.0f - thr) * 2.5f
                     : 1.0f - (1.0f - thr) * 0.4f;
    cnt = 0;
    for (int f = lane; f < NF4; f += 64) filt(h4[f], f);   // h-only rescan
    ++attempt;
  }
  const int tl = (cnt < SLOTS) ? cnt : SLOTS;

  // ---- phase 2: gather candidate lanes, exact keys, rank positives ----
  const bool active = (lane < tl);
  const int  f = active ? fbuf[lane] : 0;
  float4 h = h4[f];
  float4 v = y4[f];
  uint64_t k0 = mkkey(h.x, 4 * f),     k1 = mkkey(h.y, 4 * f + 1);
  uint64_t k2 = mkkey(h.z, 4 * f + 2), k3 = mkkey(h.w, 4 * f + 3);
  const bool ve0 = active && (h.x > thr), ve1 = active && (h.y > thr);
  const bool ve2 = active && (h.z > thr), ve3 = active && (h.w > thr);
  int pmask = (ve0 && v.x != 0.0f) ? 1 : 0;
  pmask |= (ve1 && v.y != 0.0f) ? 2 : 0;
  pmask |= (ve2 && v.z != 0.0f) ? 4 : 0;
  pmask |= (ve3 && v.w != 0.0f) ? 8 : 0;

  float tpk[4] = {0.f, 0.f, 0.f, 0.f};
  unsigned long long pl = __ballot(pmask != 0);
  while (pl) {                                   // ~0.35 iterations/row avg
    int s = __builtin_ctzll(pl);
    pl &= pl - 1;
    int flags = __shfl(pmask, s, 64);
    uint64_t pk0 = __shfl((unsigned long long)k0, s, 64);
    uint64_t pk1 = __shfl((unsigned long long)k1, s, 64);
    uint64_t pk2 = __shfl((unsigned long long)k2, s, 64);
    uint64_t pk3 = __shfl((unsigned long long)k3, s, 64);
    #pragma unroll
    for (int e = 0; e < 4; ++e) {
      if (flags & (1 << e)) {                    // wave-uniform branch
        uint64_t pk = (e == 0) ? pk0 : (e == 1) ? pk1 : (e == 2) ? pk2 : pk3;
        int c = (ve0 && k0 > pk) + (ve1 && k1 > pk) +
                (ve2 && k2 > pk) + (ve3 && k3 > pk);
        #pragma unroll
        for (int sh = 32; sh >= 1; sh >>= 1) c += __shfl_xor(c, sh, 64);
        tpk[0] += (c < 5);  tpk[1] += (c < 10);
        tpk[2] += (c < 15); tpk[3] += (c < 20);
      }
    }
  }

  // ---- wave reductions for ce and n_pos ----
  #pragma unroll
  for (int sh = 32; sh >= 1; sh >>= 1) {
    logsum += __shfl_xor(logsum, sh, 64);
    nposf  += __shfl_xor(nposf, sh, 64);
  }

  if (lane == 0) {
    float* bk = bucket + (size_t)(row & (NBUCKET - 1)) * NQ;
    float ce = -logsum / (length[b] * (float)BB);
    atomicAdd(bk + 0, ce);
    atomicAdd(bk + 1, tpk[0]);
    atomicAdd(bk + 2, tpk[1]);
    atomicAdd(bk + 3, tpk[2]);
    atomicAdd(bk + 4, tpk[3]);
    atomicAdd(bk + 5, nposf);
    atomicAdd(bk + 6, nposf);
    atomicAdd(bk + 7, nposf);
    atomicAdd(bk + 8, nposf);
  }
}

__global__ __launch_bounds__(64) void reduce_kernel(const float* __restrict__ bucket,
                                                    float* __restrict__ out) {
  const int lane = threadIdx.x;  // 64 lanes, one bucket each
  float acc[NQ];
  #pragma unroll
  for (int q = 0; q < NQ; ++q) acc[q] = bucket[lane * NQ + q];
  #pragma unroll
  for (int q = 0; q < NQ; ++q) {
    #pragma unroll
    for (int s = 32; s >= 1; s >>= 1) acc[q] += __shfl_xor(acc[q], s, 64);
  }
  if (lane == 0) {
    #pragma unroll
    for (int q = 0; q < NQ; ++q) out[q] = acc[q];
  }
}

extern "C" void kernel_launch(void* const* d_in, const int* in_sizes, int n_in,
                              void* d_out, int out_size, void* d_ws, size_t ws_size,
                              hipStream_t stream) {
  const float* yhat = (const float*)d_in[0];
  const float* yy   = (const float*)d_in[1];
  const float* len  = (const float*)d_in[2];
  float* out    = (float*)d_out;
  float* bucket = (float*)d_ws;   // NBUCKET*NQ floats = 2304 B

  hipMemsetAsync(bucket, 0, NBUCKET * NQ * sizeof(float), stream);
  pass_kernel<<<NROWS / 4, 256, 0, stream>>>(yhat, yy, len, bucket);
  reduce_kernel<<<1, 64, 0, stream>>>(bucket, out);
}